// Round 2
// baseline (454.208 us; speedup 1.0000x reference)
//
#include <hip/hip_runtime.h>

// out[n][h] = sum_k x[n][k] * W[h][k] + b[h]
// N = 4194304 rows, K = 64, H = 64, fp32 in/out, bf16 MFMA compute.
//
// Operand-swapped MFMA: D = A(W) * B(x^T) so that each lane's 4 accumulator
// regs are CONTIGUOUS in h -> vectorized dwordx4 stores (4 per pass vs 16
// scalar stores in the previous version). Per-lane load addresses identical
// to the unswapped version (A/B fragment layouts are symmetric).

typedef short bf16x8 __attribute__((ext_vector_type(8)));   // 8 bf16 in 4 VGPRs
typedef float f32x4  __attribute__((ext_vector_type(4)));

#define N_ROWS        4194304
#define ROWS_PER_BLK  512          // 4 waves * 16 rows * 8 passes
#define PASSES        8
#define NUM_BLOCKS    (N_ROWS / ROWS_PER_BLK)   // 8192

static __device__ __forceinline__ unsigned short f2bf(float f) {
    // round-to-nearest-even fp32 -> bf16 (inputs are finite normals)
    unsigned int u = __builtin_bit_cast(unsigned int, f);
    u += 0x7FFFu + ((u >> 16) & 1u);
    return (unsigned short)(u >> 16);
}

static __device__ __forceinline__ bf16x8 pack_bf16x8(f32x4 lo, f32x4 hi) {
    bf16x8 r;
    r[0] = (short)f2bf(lo[0]); r[1] = (short)f2bf(lo[1]);
    r[2] = (short)f2bf(lo[2]); r[3] = (short)f2bf(lo[3]);
    r[4] = (short)f2bf(hi[0]); r[5] = (short)f2bf(hi[1]);
    r[6] = (short)f2bf(hi[2]); r[7] = (short)f2bf(hi[3]);
    return r;
}

__global__ __launch_bounds__(256) void
leaf_linear_kernel(const float* __restrict__ x,
                   const float* __restrict__ W,
                   const float* __restrict__ b,
                   float* __restrict__ out) {
    const int tid  = threadIdx.x;
    const int wave = tid >> 6;          // 0..3
    const int lane = tid & 63;
    const int lr   = lane & 15;         // A-row (h within tile) / B-col (n within 16)
    const int g    = lane >> 4;         // 0..3 -> k group (8 elems each)

    // ---- A operand: W fragments, loaded once; W is L2-resident ----
    // A[row][k] with row = h-in-tile = lr (tile t: h = 16t+lr), k = 32s + 8g + j
    bf16x8 aw[4][2];
    f32x4  bias[4];
#pragma unroll
    for (int t = 0; t < 4; ++t) {
        // acc row r corresponds to h = 16t + 4g + r -> vector bias load
        bias[t] = *(const f32x4*)(b + t * 16 + g * 4);
#pragma unroll
        for (int s = 0; s < 2; ++s) {
            const float* wp = W + (t * 16 + lr) * 64 + s * 32 + g * 8;
            f32x4 w0 = *(const f32x4*)(wp);
            f32x4 w1 = *(const f32x4*)(wp + 4);
            aw[t][s] = pack_bf16x8(w0, w1);
        }
    }

    // ---- per-pass pointers ----
    long long blk_row0 = (long long)blockIdx.x * ROWS_PER_BLK;
    const float* xp = x + (blk_row0 + wave * 16 + lr) * 64 + g * 8;  // B: lane's n-row
    float*       op = out + (blk_row0 + wave * 16 + lr) * 64 + g * 4; // lane's out row, h base 4g

#pragma unroll
    for (int p = 0; p < PASSES; ++p) {
        // ---- load B tile (x^T): lane holds x[n][k], k = 8g+{0..7} and 32+8g+{0..7}
        f32x4 a0 = *(const f32x4*)(xp + 0);
        f32x4 a1 = *(const f32x4*)(xp + 4);
        f32x4 a2 = *(const f32x4*)(xp + 32);
        f32x4 a3 = *(const f32x4*)(xp + 36);
        bf16x8 bx[2];
        bx[0] = pack_bf16x8(a0, a1);   // k-step 0
        bx[1] = pack_bf16x8(a2, a3);   // k-step 1

        // ---- D[h-tile][n]: row (h') = 4g + r, col (n) = lr; bias in C
        f32x4 acc[4];
#pragma unroll
        for (int t = 0; t < 4; ++t) acc[t] = bias[t];
#pragma unroll
        for (int t = 0; t < 4; ++t) {
#pragma unroll
            for (int s = 0; s < 2; ++s)
                acc[t] = __builtin_amdgcn_mfma_f32_16x16x32_bf16(aw[t][s], bx[s], acc[t], 0, 0, 0);
        }

        // ---- store: lane lr writes out[n0+lr][16t+4g .. 16t+4g+3] as one dwordx4
#pragma unroll
        for (int t = 0; t < 4; ++t)
            __builtin_nontemporal_store(acc[t], (f32x4*)(op + t * 16));

        xp += 64 * 64;   // advance 64 rows
        op += 64 * 64;
    }
}

extern "C" void kernel_launch(void* const* d_in, const int* in_sizes, int n_in,
                              void* d_out, int out_size, void* d_ws, size_t ws_size,
                              hipStream_t stream) {
    const float* x = (const float*)d_in[0];
    const float* W = (const float*)d_in[1];
    const float* b = (const float*)d_in[2];
    float* out = (float*)d_out;
    leaf_linear_kernel<<<NUM_BLOCKS, 256, 0, stream>>>(x, W, b, out);
}

// Round 3
// 426.892 us; speedup vs baseline: 1.0640x; 1.0640x over previous
//
#include <hip/hip_runtime.h>

// out[n][h] = sum_k x[n][k] * W[h][k] + b[h]
// N = 4194304 rows, K = 64, H = 64, fp32 in/out, bf16 MFMA compute.
//
// Operand-swapped MFMA: D = A(W) * B(x^T) -> each lane's 4 acc regs are
// contiguous in h -> 4 dwordx4 stores per pass (plain stores; the R2
// nontemporal hint regressed 432->454us and is removed). Explicit 1-pass
// register prefetch of the x stream keeps ~8 load instrs in flight.

typedef short bf16x8 __attribute__((ext_vector_type(8)));   // 8 bf16 in 4 VGPRs
typedef float f32x4  __attribute__((ext_vector_type(4)));

#define N_ROWS        4194304
#define ROWS_PER_BLK  512          // 4 waves * 16 rows * 8 passes
#define PASSES        8
#define NUM_BLOCKS    (N_ROWS / ROWS_PER_BLK)   // 8192

static __device__ __forceinline__ unsigned short f2bf(float f) {
    // round-to-nearest-even fp32 -> bf16 (inputs are finite normals)
    unsigned int u = __builtin_bit_cast(unsigned int, f);
    u += 0x7FFFu + ((u >> 16) & 1u);
    return (unsigned short)(u >> 16);
}

static __device__ __forceinline__ bf16x8 pack_bf16x8(f32x4 lo, f32x4 hi) {
    bf16x8 r;
    r[0] = (short)f2bf(lo[0]); r[1] = (short)f2bf(lo[1]);
    r[2] = (short)f2bf(lo[2]); r[3] = (short)f2bf(lo[3]);
    r[4] = (short)f2bf(hi[0]); r[5] = (short)f2bf(hi[1]);
    r[6] = (short)f2bf(hi[2]); r[7] = (short)f2bf(hi[3]);
    return r;
}

__global__ __launch_bounds__(256) void
leaf_linear_kernel(const float* __restrict__ x,
                   const float* __restrict__ W,
                   const float* __restrict__ b,
                   float* __restrict__ out) {
    const int tid  = threadIdx.x;
    const int wave = tid >> 6;          // 0..3
    const int lane = tid & 63;
    const int lr   = lane & 15;         // A-row (h within tile) / B-col (n within 16)
    const int g    = lane >> 4;         // 0..3 -> k group (8 elems each)

    // ---- A operand: W fragments, loaded once; W is L2/L3-resident ----
    // A[row][k] with row = h-in-tile = lr (tile t: h = 16t+lr), k = 32s + 8g + j
    bf16x8 aw[4][2];
    f32x4  bias[4];
#pragma unroll
    for (int t = 0; t < 4; ++t) {
        // acc row r corresponds to h = 16t + 4g + r -> vector bias load
        bias[t] = *(const f32x4*)(b + t * 16 + g * 4);
#pragma unroll
        for (int s = 0; s < 2; ++s) {
            const float* wp = W + (t * 16 + lr) * 64 + s * 32 + g * 8;
            f32x4 w0 = *(const f32x4*)(wp);
            f32x4 w1 = *(const f32x4*)(wp + 4);
            aw[t][s] = pack_bf16x8(w0, w1);
        }
    }

    // ---- per-pass pointers ----
    long long blk_row0 = (long long)blockIdx.x * ROWS_PER_BLK;
    const float* xp = x + (blk_row0 + wave * 16 + lr) * 64 + g * 8;   // B: lane's n-row
    float*       op = out + (blk_row0 + wave * 16 + lr) * 64 + g * 4; // lane's out row

    // ---- software pipeline: loads for pass p+1 issue before pass p compute ----
    f32x4 c0 = *(const f32x4*)(xp + 0);
    f32x4 c1 = *(const f32x4*)(xp + 4);
    f32x4 c2 = *(const f32x4*)(xp + 32);
    f32x4 c3 = *(const f32x4*)(xp + 36);

#pragma unroll
    for (int p = 0; p < PASSES; ++p) {
        f32x4 n0, n1, n2, n3;
        if (p + 1 < PASSES) {
            const float* xn = xp + 64 * 64;
            n0 = *(const f32x4*)(xn + 0);
            n1 = *(const f32x4*)(xn + 4);
            n2 = *(const f32x4*)(xn + 32);
            n3 = *(const f32x4*)(xn + 36);
        }

        bf16x8 bx[2];
        bx[0] = pack_bf16x8(c0, c1);   // k-step 0 (k = 8g..8g+7)
        bx[1] = pack_bf16x8(c2, c3);   // k-step 1 (k = 32+8g..+7)

        f32x4 acc[4];
#pragma unroll
        for (int t = 0; t < 4; ++t) acc[t] = bias[t];
#pragma unroll
        for (int t = 0; t < 4; ++t) {
#pragma unroll
            for (int s = 0; s < 2; ++s)
                acc[t] = __builtin_amdgcn_mfma_f32_16x16x32_bf16(aw[t][s], bx[s], acc[t], 0, 0, 0);
        }

        // lane writes out[n0+lr][16t+4g .. +3] as one dwordx4 (plain store)
#pragma unroll
        for (int t = 0; t < 4; ++t)
            *(f32x4*)(op + t * 16) = acc[t];

        c0 = n0; c1 = n1; c2 = n2; c3 = n3;
        xp += 64 * 64;   // advance 64 rows
        op += 64 * 64;
    }
}

extern "C" void kernel_launch(void* const* d_in, const int* in_sizes, int n_in,
                              void* d_out, int out_size, void* d_ws, size_t ws_size,
                              hipStream_t stream) {
    const float* x = (const float*)d_in[0];
    const float* W = (const float*)d_in[1];
    const float* b = (const float*)d_in[2];
    float* out = (float*)d_out;
    leaf_linear_kernel<<<NUM_BLOCKS, 256, 0, stream>>>(x, W, b, out);
}

// Round 4
// 422.904 us; speedup vs baseline: 1.0740x; 1.0094x over previous
//
#include <hip/hip_runtime.h>

// out[n][h] = sum_k x[n][k] * W[h][k] + b[h]
// N = 4194304 rows, K = 64, H = 64, fp32 in/out, bf16 MFMA compute.
//
// R4: dense-read staging. The MFMA B-fragment needs lane (lr,g) to hold
// k=8g..8g+7 (32B at stride 32B for fp32) -> direct global loads are only
// 50% dense per instruction. Instead stage each wave's 16x64 fp32 tile via
// global_load_lds (linear LDS dest, XOR-pre-swizzled global source so each
// staging instruction reads a fully dense 1KB), then ds_read_b128 the
// fragments with the matching XOR swizzle (rule: both-sides-or-neither).
// Per-wave double buffer, counted vmcnt (8 steady / 4 tail), no barriers
// (LDS is wave-private).

typedef short bf16x8 __attribute__((ext_vector_type(8)));   // 8 bf16 in 4 VGPRs
typedef float f32x4  __attribute__((ext_vector_type(4)));

#define N_ROWS        4194304
#define ROWS_PER_BLK  512          // 4 waves * 16 rows * 8 passes
#define PASSES        8
#define NUM_BLOCKS    (N_ROWS / ROWS_PER_BLK)   // 8192

typedef const unsigned int __attribute__((address_space(1)))* gp_t;
typedef unsigned int __attribute__((address_space(3)))* lp_t;

static __device__ __forceinline__ unsigned short f2bf(float f) {
    // round-to-nearest-even fp32 -> bf16 (inputs are finite normals)
    unsigned int u = __builtin_bit_cast(unsigned int, f);
    u += 0x7FFFu + ((u >> 16) & 1u);
    return (unsigned short)(u >> 16);
}

static __device__ __forceinline__ bf16x8 pack_bf16x8(f32x4 lo, f32x4 hi) {
    bf16x8 r;
    r[0] = (short)f2bf(lo[0]); r[1] = (short)f2bf(lo[1]);
    r[2] = (short)f2bf(lo[2]); r[3] = (short)f2bf(lo[3]);
    r[4] = (short)f2bf(hi[0]); r[5] = (short)f2bf(hi[1]);
    r[6] = (short)f2bf(hi[2]); r[7] = (short)f2bf(hi[3]);
    return r;
}

__global__ __launch_bounds__(256) void
leaf_linear_kernel(const float* __restrict__ x,
                   const float* __restrict__ W,
                   const float* __restrict__ b,
                   float* __restrict__ out) {
    // [wave][dbuf][16 rows x 64 floats], swizzled: lds[r][c'] = x[r][c'^((r&7)<<2)]
    __shared__ __align__(16) float lds[4][2][1024];

    const int tid  = threadIdx.x;
    const int wave = tid >> 6;          // 0..3
    const int lane = tid & 63;
    const int lr   = lane & 15;         // A-row (h within tile) / B-col (n within 16)
    const int g    = lane >> 4;         // 0..3 -> k group (8 elems each)

    // ---- A operand: W fragments + bias, loaded once; W is L2/L3-resident ----
    bf16x8 aw[4][2];
    f32x4  bias[4];
#pragma unroll
    for (int t = 0; t < 4; ++t) {
        bias[t] = *(const f32x4*)(b + t * 16 + g * 4);
#pragma unroll
        for (int s2 = 0; s2 < 2; ++s2) {
            const float* wp = W + (t * 16 + lr) * 64 + s2 * 32 + g * 8;
            f32x4 w0 = *(const f32x4*)(wp);
            f32x4 w1 = *(const f32x4*)(wp + 4);
            aw[t][s2] = pack_bf16x8(w0, w1);
        }
    }

    // ---- staging source offsets (floats within 16x64 tile), XOR-pre-swizzled
    // stage instr i: lane l -> LDS float i*256 + l*4 + j  (row = i*4 + l/16)
    int srcoff[4];
#pragma unroll
    for (int i = 0; i < 4; ++i) {
        const int rl = i * 4 + (lane >> 4);
        srcoff[i] = rl * 64 + (((lane & 15) * 4) ^ ((rl & 7) << 2));
    }

    // ---- ds_read offsets (floats within a row), matching XOR swizzle
    const int sw = (lr & 7) << 2;
    const int o0 = (8 * g) ^ sw;        // k-step0 quad 0  (cols 8g..8g+3)
    const int o1 = o0 ^ 4;              // k-step0 quad 1  (cols 8g+4..8g+7)

    const long long blk0 = (long long)blockIdx.x * ROWS_PER_BLK;
    const float* xw = x + (blk0 + wave * 16) * 64;                    // wave pass-0 tile
    float*       op = out + (blk0 + wave * 16 + lr) * 64 + g * 4;     // lane's out row

    // ---- prologue: stage pass 0 into buf 0, drain
#pragma unroll
    for (int i = 0; i < 4; ++i)
        __builtin_amdgcn_global_load_lds((gp_t)(const void*)(xw + srcoff[i]),
                                         (lp_t)(void*)&lds[wave][0][i * 256], 16, 0, 0);
    asm volatile("s_waitcnt vmcnt(0)" ::: "memory");

    for (int p = 0; p < PASSES; ++p) {
        const int buf = p & 1;
        if (p + 1 < PASSES) {
            // issue next tile's 4 dense staging loads, then wait so only the
            // newest 8 VMEM ops (4 stores of p-1 + 4 stages of p+1) may remain
            const float* xn = xw + (p + 1) * 4096;
#pragma unroll
            for (int i = 0; i < 4; ++i)
                __builtin_amdgcn_global_load_lds((gp_t)(const void*)(xn + srcoff[i]),
                                                 (lp_t)(void*)&lds[wave][buf ^ 1][i * 256], 16, 0, 0);
            asm volatile("s_waitcnt vmcnt(8)" ::: "memory");
        } else {
            asm volatile("s_waitcnt vmcnt(4)" ::: "memory");
        }

        // ---- fragments from LDS (b128 reads, structurally conflict-free)
        const float* base = &lds[wave][buf][lr * 64];
        f32x4 r0 = *(const f32x4*)(base + o0);
        f32x4 r1 = *(const f32x4*)(base + o1);
        f32x4 r2 = *(const f32x4*)(base + 32 + o0);
        f32x4 r3 = *(const f32x4*)(base + 32 + o1);

        bf16x8 bx[2];
        bx[0] = pack_bf16x8(r0, r1);   // k = 8g..8g+7
        bx[1] = pack_bf16x8(r2, r3);   // k = 32+8g..+7

        f32x4 acc[4];
#pragma unroll
        for (int t = 0; t < 4; ++t) acc[t] = bias[t];
#pragma unroll
        for (int t = 0; t < 4; ++t) {
#pragma unroll
            for (int s2 = 0; s2 < 2; ++s2)
                acc[t] = __builtin_amdgcn_mfma_f32_16x16x32_bf16(aw[t][s2], bx[s2], acc[t], 0, 0, 0);
        }

        // ---- store: lane lr writes out[n][16t+4g .. +3] as one dwordx4
#pragma unroll
        for (int t = 0; t < 4; ++t)
            *(f32x4*)(op + t * 16) = acc[t];

        op += 64 * 64;
    }
}

extern "C" void kernel_launch(void* const* d_in, const int* in_sizes, int n_in,
                              void* d_out, int out_size, void* d_ws, size_t ws_size,
                              hipStream_t stream) {
    const float* x = (const float*)d_in[0];
    const float* W = (const float*)d_in[1];
    const float* b = (const float*)d_in[2];
    float* out = (float*)d_out;
    leaf_linear_kernel<<<NUM_BLOCKS, 256, 0, stream>>>(x, W, b, out);
}